// Round 9
// baseline (203.916 us; speedup 1.0000x reference)
//
#include <hip/hip_runtime.h>
#include <hip/hip_bf16.h>
#include <math.h>

#define Ddim 1024
#define Mrows 4096
#define Ncols 8192
#define BM 128
#define BN 128
#define BK 32
#define NCS 64                         // 64 col-split blocks of 128 cols
#define CS 64                          // lse partials per row (128 cols each)
#define RT (Mrows / BM)                // 32
#define KITERS (Ddim / BK)             // 32
#define NSOLVE 256                     // hungarian solve blocks (dispatch 1st)
#define SCALE 20.0f                    // 1/TEMPERATURE
#define DOTS_PAD 132                   // f32 words per staged row (528B, 16B-aligned)

typedef __bf16 bf16_t;
typedef __bf16 bf16x8 __attribute__((ext_vector_type(8)));
typedef float f32x4 __attribute__((ext_vector_type(4)));

// uniform-lane-index cross-lane reads: v_readlane (VALU latency), NOT
// ds_bpermute (LDS latency). Index must be wave-uniform — all ours are.
__device__ __forceinline__ int rdlane_i(int v, int lane) {
  return __builtin_amdgcn_readlane(v, lane);
}
__device__ __forceinline__ float rdlane_f(float v, int lane) {
  return __int_as_float(__builtin_amdgcn_readlane(__float_as_int(v), lane));
}
__device__ __forceinline__ float rdfirst_f(float v) {
  return __int_as_float(__builtin_amdgcn_readfirstlane(__float_as_int(v)));
}

// DPP row_ror:N argmin step — combines lane x with lane (x+N) mod 16 inside
// each 16-lane DPP row. Lexicographic (val, idx) min.
template <int N>
__device__ __forceinline__ void argmin_ror(float& cand, int& idx) {
  const float ov = __int_as_float(__builtin_amdgcn_update_dpp(
      __float_as_int(cand), __float_as_int(cand), 0x120 | N, 0xf, 0xf, false));
  const int oi = __builtin_amdgcn_update_dpp(idx, idx, 0x120 | N, 0xf, 0xf, false);
  if (ov < cand || (ov == cand && oi < idx)) { cand = ov; idx = oi; }
}

// ---------------------------------------------------------------------------
// Kernel 0 (MEGA): blocks 0..255 = LDS-staged exact-fp32 16x16 dots + JV
// solve; blocks 256..2303 = bf16 GEMM + partial-LSE. Solve blocks dispatch
// FIRST so their dependent chain hides under the GEMM.
//
// Change this round (vs round-5 passing kernel): the f32->bf16 cvt kernel is
// GONE. The GEMM reg-stages its tiles straight from the f32 inputs: per
// K-step each thread loads its 32B f32 chunk (2x float4), converts with the
// SAME (bf16_t) cast the cvt kernel used (bit-identical bf16 -> bit-identical
// sim -> identical output), and ds_write_b128s into the same swizzled LDS
// layout the DMA produced (fragment readers untouched). T14 schedule, plain
// barriers only (R8 lesson: raw s_barrier/counted-vmcnt structures kill the
// container; never again here): top of iter kc writes tile kc+1 (held in
// regs) into buf p^1 (readers finished at the kc-1 barrier), issues loads
// for tile kc+2, MFMAs buf p, ONE __syncthreads. Loads get a full iteration
// of MFMA+barrier to land — same hiding window as the old global_load_lds.
//
// Key identity: sum_matched lse == sum_all_rows lse (p is a permutation per
// block), so the solve only contributes -sum(C_matched)/4096; the lse term
// attaches in lse_sum_kernel afterwards.
// ---------------------------------------------------------------------------
__global__ __launch_bounds__(256, 4) void mega_kernel(
    const float* __restrict__ o, const float* __restrict__ pos,
    const float* __restrict__ neg,
    float* __restrict__ pm, float* __restrict__ pl, float* __restrict__ out)
{
  __shared__ bf16_t As[2][BM * BK];   // 2 x 8 KB (gemm path)
  __shared__ bf16_t Bs[2][BN * BK];   // 2 x 8 KB
  __shared__ float Csolve[16][16];    // 1 KB (solve path)

  if (blockIdx.x < NSOLVE) {
    // ---------------- diagonal 16x16 dots (exact fp32, LDS-staged) --------
    const int b = blockIdx.x;
    float* o_s = (float*)(&As[0][0]);         // [16][DOTS_PAD] overlay
    float* p_s = (float*)(&Bs[0][0]);         // [16][DOTS_PAD]
    const int di = threadIdx.x >> 4;
    const int dj = threadIdx.x & 15;
    float s0 = 0.f, s1 = 0.f, s2 = 0.f, s3 = 0.f;
    for (int k0 = 0; k0 < Ddim; k0 += 128) {
      __syncthreads();   // protect previous chunk's reads
#pragma unroll
      for (int rp = 0; rp < 4; ++rp) {
        const int fid = threadIdx.x + 256 * rp;   // 0..1023 float4 slots
        const int arr = fid >> 9;                 // 0 = o, 1 = pos
        const int row = (fid >> 5) & 15;
        const int c4 = fid & 31;
        const float* src = arr ? pos : o;
        float* dst = arr ? p_s : o_s;
        const float4 v =
            *(const float4*)(src + (size_t)(b * 16 + row) * Ddim + k0 + c4 * 4);
        *(float4*)(dst + row * DOTS_PAD + c4 * 4) = v;
      }
      __syncthreads();
#pragma unroll
      for (int kk = 0; kk < 128; kk += 4) {
        const float4 a = *(const float4*)(o_s + di * DOTS_PAD + kk);
        const float4 e = *(const float4*)(p_s + dj * DOTS_PAD + kk);
        s0 = fmaf(a.x, e.x, s0); s1 = fmaf(a.y, e.y, s1);
        s2 = fmaf(a.z, e.z, s2); s3 = fmaf(a.w, e.w, s3);
      }
    }
    Csolve[di][dj] = (s0 + s1 + s2 + s3) * SCALE;
    __syncthreads();
    if (threadIdx.x >= 64) return;

    // ---------------- Hungarian solve (readlane + DPP) --------------------
    const int L = threadIdx.x;          // lane; lanes 0..15 = cols 1..16
    const float INF = 3.0e38f;
    float vj = 0.f, u_reg = 0.f;        // v[L+1], u[L+1]
    int pj = 0;                         // p[L+1] (0 = unmatched)
    float minv = INF;
    int wayj = 0;
    bool usedj = false, on_tree = false;

    for (int i = 1; i <= 16; ++i) {
      minv = INF; wayj = 0; usedj = false; on_tree = false;
      int j0 = 0;                       // scalar; 0 = dummy root column
      while (true) {
        usedj = usedj || (L + 1 == j0);
        const int i0 = (j0 == 0) ? i : rdlane_i(pj, j0 - 1);
        on_tree = on_tree || (L + 1 == i0);
        const float ui0 = rdlane_f(u_reg, i0 - 1);
        if (!usedj) {
          const float cur = -Csolve[i0 - 1][L & 15] - ui0 - vj;
          if (cur < minv) { minv = cur; wayj = j0; }
        }
        float cand = (L < 16 && !usedj) ? minv : INF;
        int idx = L;
        argmin_ror<8>(cand, idx);
        argmin_ror<4>(cand, idx);
        argmin_ror<2>(cand, idx);
        argmin_ror<1>(cand, idx);
        const float delta = rdfirst_f(cand);
        const int j1 = __builtin_amdgcn_readfirstlane(idx) + 1;  // 1..16
        if (usedj) vj -= delta; else minv -= delta;
        if (on_tree) u_reg += delta;
        j0 = j1;
        if (rdlane_i(pj, j0 - 1) == 0) break;
      }
      // augment along way[] chain back to the root
      while (j0 != 0) {
        const int j1a = rdlane_i(wayj, j0 - 1);
        const int pjn = (j1a == 0) ? i : rdlane_i(pj, (j1a > 0) ? j1a - 1 : 0);
        if (L == j0 - 1) pj = pjn;
        j0 = j1a;
      }
    }

    float loss = (L < 16) ? -Csolve[pj - 1][L] : 0.f;
#pragma unroll
    for (int off = 8; off > 0; off >>= 1) loss += __shfl_down(loss, off, 64);
    if (L == 0) atomicAdd(out, loss * (1.0f / 4096.0f));
    return;
  }

  // ------------------------- GEMM + partial-LSE path ----------------------
  const int bid = blockIdx.x - NSOLVE;
  const int rt = bid >> 6;        // 0..31
  const int cs = bid & 63;        // 0..63
  const int row0 = rt * BM;
  const float* Eb = (cs < 32) ? (pos + (size_t)cs * BN * Ddim)
                              : (neg + (size_t)(cs - 32) * BN * Ddim);

  const int t = threadIdx.x;
  const int wave = t >> 6;
  const int lane = t & 63;
  const int quad = lane >> 4;
  const int l16 = lane & 15;
  const int koff = ((quad ^ ((l16 >> 1) & 3)) << 3);   // fragment chunk offset
  const int lr4 = lane >> 2;                            // staging row-in-16
  const int cstg = lane & 3;                            // staging chunk id

  f32x4 acc[2][8];
#pragma unroll
  for (int a = 0; a < 2; ++a)
#pragma unroll
    for (int b2 = 0; b2 < 8; ++b2) acc[a][b2] = (f32x4){0.f, 0.f, 0.f, 0.f};

  // reg-staged f32 tile: this thread owns rows wave*32+cl*16+lr4, 32B chunk
  // gc (pre-swizzled global col) -> LDS chunk cstg. Same layout the DMA made.
  float4 ra[2][2], rb[2][2];

#define STAGE_LOAD(k0)                                                       \
  {                                                                          \
    _Pragma("unroll")                                                        \
    for (int cl = 0; cl < 2; ++cl) {                                         \
      const int r = wave * 32 + cl * 16 + lr4;                               \
      const int gc = cstg ^ ((r >> 1) & 3);                                  \
      const float* pa = o + (size_t)(row0 + r) * Ddim + (k0) + gc * 8;       \
      const float* pe = Eb + (size_t)r * Ddim + (k0) + gc * 8;               \
      ra[cl][0] = *(const float4*)(pa);                                      \
      ra[cl][1] = *(const float4*)(pa + 4);                                  \
      rb[cl][0] = *(const float4*)(pe);                                      \
      rb[cl][1] = *(const float4*)(pe + 4);                                  \
    }                                                                        \
  }

#define STAGE_WRITE(pp)                                                      \
  {                                                                          \
    _Pragma("unroll")                                                        \
    for (int cl = 0; cl < 2; ++cl) {                                         \
      const int r = wave * 32 + cl * 16 + lr4;                               \
      const bf16x8 va = {(bf16_t)ra[cl][0].x, (bf16_t)ra[cl][0].y,           \
                         (bf16_t)ra[cl][0].z, (bf16_t)ra[cl][0].w,           \
                         (bf16_t)ra[cl][1].x, (bf16_t)ra[cl][1].y,           \
                         (bf16_t)ra[cl][1].z, (bf16_t)ra[cl][1].w};          \
      const bf16x8 vb = {(bf16_t)rb[cl][0].x, (bf16_t)rb[cl][0].y,           \
                         (bf16_t)rb[cl][0].z, (bf16_t)rb[cl][0].w,           \
                         (bf16_t)rb[cl][1].x, (bf16_t)rb[cl][1].y,           \
                         (bf16_t)rb[cl][1].z, (bf16_t)rb[cl][1].w};          \
      *(bf16x8*)(&As[pp][r * BK + cstg * 8]) = va;                           \
      *(bf16x8*)(&Bs[pp][r * BK + cstg * 8]) = vb;                           \
    }                                                                        \
  }

  // prologue: tile 0 -> buf 0 (through regs), tile 1 -> regs.
  STAGE_LOAD(0);
  STAGE_WRITE(0);
  STAGE_LOAD(BK);
  __syncthreads();   // buf0 visible to all waves

  int p = 0;
  for (int kc = 0; kc < KITERS; ++kc) {
    // write tile kc+1 (in regs) into buf p^1 — its last readers finished
    // before the barrier that ended iter kc-1.
    if (kc + 1 < KITERS) STAGE_WRITE(p ^ 1);
    // issue loads for tile kc+2 — a full iteration (MFMA + barrier) to land.
    if (kc + 2 < KITERS) STAGE_LOAD((kc + 2) * BK);

    const int rowA0 = wave * 32 + l16;
    const bf16x8 a0 = *(const bf16x8*)(&As[p][rowA0 * BK + koff]);
    const bf16x8 a1 = *(const bf16x8*)(&As[p][(rowA0 + 16) * BK + koff]);
#pragma unroll
    for (int fn = 0; fn < 8; ++fn) {
      const bf16x8 bf = *(const bf16x8*)(&Bs[p][(fn * 16 + l16) * BK + koff]);
      acc[0][fn] = __builtin_amdgcn_mfma_f32_16x16x32_bf16(a0, bf, acc[0][fn], 0, 0, 0);
      acc[1][fn] = __builtin_amdgcn_mfma_f32_16x16x32_bf16(a1, bf, acc[1][fn], 0, 0, 0);
    }
    if (kc + 1 < KITERS) __syncthreads();
    p ^= 1;
  }

  // epilogue: per-row (m, l) over this block's 128 cols.
  // C/D: col = fn*16 + l16, row = wave*32 + fm*16 + quad*4 + r
#pragma unroll
  for (int fm = 0; fm < 2; ++fm) {
#pragma unroll
    for (int r = 0; r < 4; ++r) {
      float s[8];
#pragma unroll
      for (int fn = 0; fn < 8; ++fn) s[fn] = acc[fm][fn][r] * SCALE;
      float m = s[0];
#pragma unroll
      for (int fn = 1; fn < 8; ++fn) m = fmaxf(m, s[fn]);
#pragma unroll
      for (int off = 1; off <= 8; off <<= 1)
        m = fmaxf(m, __shfl_xor(m, off, 64));   // row max over l16 group
      float l = 0.f;
#pragma unroll
      for (int fn = 0; fn < 8; ++fn) l += __expf(s[fn] - m);
#pragma unroll
      for (int off = 1; off <= 8; off <<= 1)
        l += __shfl_xor(l, off, 64);
      if (l16 == 0) {
        const int rg = row0 + wave * 32 + fm * 16 + quad * 4 + r;
        pm[(size_t)rg * CS + cs] = m;
        pl[(size_t)rg * CS + cs] = l;
      }
    }
  }
#undef STAGE_LOAD
#undef STAGE_WRITE
}

// ---------------------------------------------------------------------------
// Kernel 1: wave-per-row lse from partials (6-step shfl_xor log-sum-exp
// butterfly over the 64 partials), then atomicAdd sum(lse)/4096.
// ---------------------------------------------------------------------------
__global__ __launch_bounds__(256) void lse_sum_kernel(
    const float* __restrict__ pm, const float* __restrict__ pl,
    float* __restrict__ out)
{
  const int row = blockIdx.x * 4 + (threadIdx.x >> 6);   // 0..4095
  const int lane = threadIdx.x & 63;
  const size_t base = (size_t)row * CS + lane;
  float m = pm[base];
  float l = pl[base];
#pragma unroll
  for (int off = 32; off > 0; off >>= 1) {
    const float m2 = __shfl_xor(m, off, 64);
    const float l2 = __shfl_xor(l, off, 64);
    const float M = fmaxf(m, m2);
    l = l * __expf(m - M) + l2 * __expf(m2 - M);
    m = M;
  }
  const float v = m + logf(l);   // identical in all 64 lanes
  __shared__ float wsum[4];
  if (lane == 0) wsum[threadIdx.x >> 6] = v;
  __syncthreads();
  if (threadIdx.x == 0)
    atomicAdd(out, (wsum[0] + wsum[1] + wsum[2] + wsum[3]) * (1.0f / 4096.0f));
}

extern "C" void kernel_launch(void* const* d_in, const int* in_sizes, int n_in,
                              void* d_out, int out_size, void* d_ws, size_t ws_size,
                              hipStream_t stream) {
  const float* o   = (const float*)d_in[0];  // (256,16,1024) f32
  const float* pos = (const float*)d_in[1];
  const float* neg = (const float*)d_in[2];
  float* out = (float*)d_out;

  float* ws = (float*)d_ws;
  float* pm = ws;                         // 4096*64 = 1 MB
  float* pl = pm + (size_t)4096 * CS;     // 4096*64 = 1 MB

  hipMemsetAsync(out, 0, sizeof(float), stream);
  mega_kernel<<<NSOLVE + RT * NCS, 256, 0, stream>>>(o, pos, neg, pm, pl, out);
  lse_sum_kernel<<<4096 / 4, 256, 0, stream>>>(pm, pl, out);
}

// Round 10
// 194.552 us; speedup vs baseline: 1.0481x; 1.0481x over previous
//
#include <hip/hip_runtime.h>
#include <hip/hip_bf16.h>
#include <math.h>

#define Ddim 1024
#define Mrows 4096
#define Ncols 8192
#define BM 128
#define BN 128
#define BK 32
#define NCS 64                         // 64 col-split blocks of 128 cols
#define CS 64                          // lse partials per row (128 cols each)
#define RT (Mrows / BM)                // 32
#define KITERS (Ddim / BK)             // 32
#define NSOLVE 256                     // hungarian solve blocks (dispatch 1st)
#define SCALE 20.0f                    // 1/TEMPERATURE
#define ARR_ELEMS (Mrows * Ddim)       // 4194304 per input array
#define DOTS_PAD 132                   // f32 words per staged row (528B, 16B-aligned)

typedef __bf16 bf16_t;
typedef __bf16 bf16x8 __attribute__((ext_vector_type(8)));
typedef float f32x4 __attribute__((ext_vector_type(4)));

// global->LDS DMA, 16B per lane, lds dest = wave-uniform base + lane*16
#define LOAD16_TO_LDS(g, l)                                                  \
  __builtin_amdgcn_global_load_lds(                                          \
      (const __attribute__((address_space(1))) void*)(g),                    \
      (__attribute__((address_space(3))) void*)(l), 16, 0, 0)

// uniform-lane-index cross-lane reads: v_readlane (VALU latency), NOT
// ds_bpermute (LDS latency). Index must be wave-uniform — all ours are.
__device__ __forceinline__ int rdlane_i(int v, int lane) {
  return __builtin_amdgcn_readlane(v, lane);
}
__device__ __forceinline__ float rdlane_f(float v, int lane) {
  return __int_as_float(__builtin_amdgcn_readlane(__float_as_int(v), lane));
}
__device__ __forceinline__ float rdfirst_f(float v) {
  return __int_as_float(__builtin_amdgcn_readfirstlane(__float_as_int(v)));
}

// DPP row_ror:N argmin step — combines lane x with lane (x+N) mod 16 inside
// each 16-lane DPP row. Lexicographic (val, idx) min.
template <int N>
__device__ __forceinline__ void argmin_ror(float& cand, int& idx) {
  const float ov = __int_as_float(__builtin_amdgcn_update_dpp(
      __float_as_int(cand), __float_as_int(cand), 0x120 | N, 0xf, 0xf, false));
  const int oi = __builtin_amdgcn_update_dpp(idx, idx, 0x120 | N, 0xf, 0xf, false);
  if (ov < cand || (ov == cand && oi < idx)) { cand = ov; idx = oi; }
}

// ---------------------------------------------------------------------------
// Kernel 0: f32 -> bf16 conversion pre-pass; thread (0,0) zeroes the output.
// ---------------------------------------------------------------------------
__global__ __launch_bounds__(256) void cvt_kernel(
    const float* __restrict__ o, const float* __restrict__ pos,
    const float* __restrict__ neg, bf16_t* __restrict__ ob,
    bf16_t* __restrict__ pb, bf16_t* __restrict__ nb,
    float* __restrict__ out)
{
  if (blockIdx.x == 0 && threadIdx.x == 0) out[0] = 0.f;
  const int idx = blockIdx.x * 256 + threadIdx.x;   // 0 .. 3*ARR/8-1
  const int seg = idx >> 19;                        // ARR_ELEMS/8 = 2^19
  const int off = idx & ((1 << 19) - 1);
  const float* src = (seg == 0) ? o : (seg == 1) ? pos : neg;
  bf16_t* dst = (seg == 0) ? ob : (seg == 1) ? pb : nb;
  const float4 v0 = *(const float4*)(src + (size_t)off * 8);
  const float4 v1 = *(const float4*)(src + (size_t)off * 8 + 4);
  bf16x8 r = {(bf16_t)v0.x, (bf16_t)v0.y, (bf16_t)v0.z, (bf16_t)v0.w,
              (bf16_t)v1.x, (bf16_t)v1.y, (bf16_t)v1.z, (bf16_t)v1.w};
  *(bf16x8*)(dst + (size_t)off * 8) = r;
}

// ---------------------------------------------------------------------------
// Kernel 1 (MEGA): blocks 0..255 = LDS-staged exact-fp32 16x16 dots + JV
// solve; blocks 256..2303 = bf16 GEMM + partial-LSE. Solve blocks dispatch
// FIRST so their dependent chain hides under the GEMM.
//
// The ONLY change vs the round-5 passing kernel (198.6 us): Csolve no longer
// has its own __shared__ array — it overlays the LAST 1024 B of Bs (bytes
// 15360..16383). Static bounds: dots staging p_s spans Bs bytes 0..8447,
// o_s spans As bytes 0..8447, GEMM blocks never reference Csolve. This drops
// LDS_Block_Size 33792 -> 32768, lifting occupancy from 4 to 5 blocks/CU
// (160 KiB / 32 KiB): +25% resident waves so the per-K-step vmcnt(0)+barrier
// drain of one block overlaps another block's MFMA (m114 mechanism) — the
// identified 47%-idle stall.
//
// Key identity: sum_matched lse == sum_all_rows lse (p is a permutation per
// block), so the solve only contributes -sum(C_matched)/4096; the lse term
// attaches in lse_sum_kernel afterwards.
// ---------------------------------------------------------------------------
__global__ __launch_bounds__(256, 4) void mega_kernel(
    const bf16_t* __restrict__ ob, const bf16_t* __restrict__ pb,
    const bf16_t* __restrict__ nb, const float* __restrict__ o,
    const float* __restrict__ pos,
    float* __restrict__ pm, float* __restrict__ pl, float* __restrict__ out)
{
  __shared__ bf16_t As[2][BM * BK];   // 2 x 8 KB (gemm path)
  __shared__ bf16_t Bs[2][BN * BK];   // 2 x 8 KB; solve overlays live here

  if (blockIdx.x < NSOLVE) {
    // Csolve overlay: last 1024 B of Bs (float[16][16]); disjoint from p_s.
    float (*Csolve)[16] = (float (*)[16])((char*)&Bs[0][0] + 15360);
    // ---------------- diagonal 16x16 dots (exact fp32, LDS-staged) --------
    const int b = blockIdx.x;
    float* o_s = (float*)(&As[0][0]);         // [16][DOTS_PAD] = 8448 B
    float* p_s = (float*)(&Bs[0][0]);         // [16][DOTS_PAD] = 8448 B
    const int di = threadIdx.x >> 4;
    const int dj = threadIdx.x & 15;
    float s0 = 0.f, s1 = 0.f, s2 = 0.f, s3 = 0.f;
    for (int k0 = 0; k0 < Ddim; k0 += 128) {
      __syncthreads();   // protect previous chunk's reads
#pragma unroll
      for (int rp = 0; rp < 4; ++rp) {
        const int fid = threadIdx.x + 256 * rp;   // 0..1023 float4 slots
        const int arr = fid >> 9;                 // 0 = o, 1 = pos
        const int row = (fid >> 5) & 15;
        const int c4 = fid & 31;
        const float* src = arr ? pos : o;
        float* dst = arr ? p_s : o_s;
        const float4 v =
            *(const float4*)(src + (size_t)(b * 16 + row) * Ddim + k0 + c4 * 4);
        *(float4*)(dst + row * DOTS_PAD + c4 * 4) = v;
      }
      __syncthreads();
#pragma unroll
      for (int kk = 0; kk < 128; kk += 4) {
        const float4 a = *(const float4*)(o_s + di * DOTS_PAD + kk);
        const float4 e = *(const float4*)(p_s + dj * DOTS_PAD + kk);
        s0 = fmaf(a.x, e.x, s0); s1 = fmaf(a.y, e.y, s1);
        s2 = fmaf(a.z, e.z, s2); s3 = fmaf(a.w, e.w, s3);
      }
    }
    Csolve[di][dj] = (s0 + s1 + s2 + s3) * SCALE;
    __syncthreads();
    if (threadIdx.x >= 64) return;

    // ---------------- Hungarian solve (readlane + DPP) --------------------
    const int L = threadIdx.x;          // lane; lanes 0..15 = cols 1..16
    const float INF = 3.0e38f;
    float vj = 0.f, u_reg = 0.f;        // v[L+1], u[L+1]
    int pj = 0;                         // p[L+1] (0 = unmatched)
    float minv = INF;
    int wayj = 0;
    bool usedj = false, on_tree = false;

    for (int i = 1; i <= 16; ++i) {
      minv = INF; wayj = 0; usedj = false; on_tree = false;
      int j0 = 0;                       // scalar; 0 = dummy root column
      while (true) {
        usedj = usedj || (L + 1 == j0);
        const int i0 = (j0 == 0) ? i : rdlane_i(pj, j0 - 1);
        on_tree = on_tree || (L + 1 == i0);
        const float ui0 = rdlane_f(u_reg, i0 - 1);
        if (!usedj) {
          const float cur = -Csolve[i0 - 1][L & 15] - ui0 - vj;
          if (cur < minv) { minv = cur; wayj = j0; }
        }
        float cand = (L < 16 && !usedj) ? minv : INF;
        int idx = L;
        argmin_ror<8>(cand, idx);
        argmin_ror<4>(cand, idx);
        argmin_ror<2>(cand, idx);
        argmin_ror<1>(cand, idx);
        const float delta = rdfirst_f(cand);
        const int j1 = __builtin_amdgcn_readfirstlane(idx) + 1;  // 1..16
        if (usedj) vj -= delta; else minv -= delta;
        if (on_tree) u_reg += delta;
        j0 = j1;
        if (rdlane_i(pj, j0 - 1) == 0) break;
      }
      // augment along way[] chain back to the root
      while (j0 != 0) {
        const int j1a = rdlane_i(wayj, j0 - 1);
        const int pjn = (j1a == 0) ? i : rdlane_i(pj, (j1a > 0) ? j1a - 1 : 0);
        if (L == j0 - 1) pj = pjn;
        j0 = j1a;
      }
    }

    float loss = (L < 16) ? -Csolve[pj - 1][L] : 0.f;
#pragma unroll
    for (int off = 8; off > 0; off >>= 1) loss += __shfl_down(loss, off, 64);
    if (L == 0) atomicAdd(out, loss * (1.0f / 4096.0f));
    return;
  }

  // ------------------------- GEMM + partial-LSE path ----------------------
  const int bid = blockIdx.x - NSOLVE;
  const int rt = bid >> 6;        // 0..31
  const int cs = bid & 63;        // 0..63
  const int row0 = rt * BM;
  const bf16_t* Eb = (cs < 32) ? (pb + (size_t)cs * BN * Ddim)
                               : (nb + (size_t)(cs - 32) * BN * Ddim);

  const int t = threadIdx.x;
  const int wave = t >> 6;
  const int lane = t & 63;
  const int quad = lane >> 4;
  const int l16 = lane & 15;
  const int koff = ((quad ^ ((l16 >> 1) & 3)) << 3);   // fragment chunk offset
  const int lr4 = lane >> 2;                            // staging row-in-16
  const int cstg = lane & 3;                            // staging chunk id

  f32x4 acc[2][8];
#pragma unroll
  for (int a = 0; a < 2; ++a)
#pragma unroll
    for (int b2 = 0; b2 < 8; ++b2) acc[a][b2] = (f32x4){0.f, 0.f, 0.f, 0.f};

  // prologue: stage tile 0 into buffer 0 (each wave stages 32 rows of A & B)
#pragma unroll
  for (int cl = 0; cl < 2; ++cl) {
    const int r = wave * 32 + cl * 16 + lr4;
    const int gc = cstg ^ ((r >> 1) & 3);
    LOAD16_TO_LDS(ob + (size_t)(row0 + r) * Ddim + gc * 8,
                  &As[0][(wave * 32 + cl * 16) * BK]);
    LOAD16_TO_LDS(Eb + (size_t)r * Ddim + gc * 8,
                  &Bs[0][(wave * 32 + cl * 16) * BK]);
  }

  int p = 0;
  for (int kc = 0; kc < KITERS; ++kc) {
    __syncthreads();   // drains DMA for buf p; protects buf p^1 reuse
    if (kc + 1 < KITERS) {
      const int k0 = (kc + 1) * BK;
#pragma unroll
      for (int cl = 0; cl < 2; ++cl) {
        const int r = wave * 32 + cl * 16 + lr4;
        const int gc = cstg ^ ((r >> 1) & 3);
        LOAD16_TO_LDS(ob + (size_t)(row0 + r) * Ddim + k0 + gc * 8,
                      &As[p ^ 1][(wave * 32 + cl * 16) * BK]);
        LOAD16_TO_LDS(Eb + (size_t)r * Ddim + k0 + gc * 8,
                      &Bs[p ^ 1][(wave * 32 + cl * 16) * BK]);
      }
    }

    const int rowA0 = wave * 32 + l16;
    const bf16x8 a0 = *(const bf16x8*)(&As[p][rowA0 * BK + koff]);
    const bf16x8 a1 = *(const bf16x8*)(&As[p][(rowA0 + 16) * BK + koff]);
#pragma unroll
    for (int fn = 0; fn < 8; ++fn) {
      const bf16x8 bf = *(const bf16x8*)(&Bs[p][(fn * 16 + l16) * BK + koff]);
      acc[0][fn] = __builtin_amdgcn_mfma_f32_16x16x32_bf16(a0, bf, acc[0][fn], 0, 0, 0);
      acc[1][fn] = __builtin_amdgcn_mfma_f32_16x16x32_bf16(a1, bf, acc[1][fn], 0, 0, 0);
    }
    p ^= 1;
  }

  // epilogue: per-row (m, l) over this block's 128 cols.
  // C/D: col = fn*16 + l16, row = wave*32 + fm*16 + quad*4 + r
#pragma unroll
  for (int fm = 0; fm < 2; ++fm) {
#pragma unroll
    for (int r = 0; r < 4; ++r) {
      float s[8];
#pragma unroll
      for (int fn = 0; fn < 8; ++fn) s[fn] = acc[fm][fn][r] * SCALE;
      float m = s[0];
#pragma unroll
      for (int fn = 1; fn < 8; ++fn) m = fmaxf(m, s[fn]);
#pragma unroll
      for (int off = 1; off <= 8; off <<= 1)
        m = fmaxf(m, __shfl_xor(m, off, 64));   // row max over l16 group
      float l = 0.f;
#pragma unroll
      for (int fn = 0; fn < 8; ++fn) l += __expf(s[fn] - m);
#pragma unroll
      for (int off = 1; off <= 8; off <<= 1)
        l += __shfl_xor(l, off, 64);
      if (l16 == 0) {
        const int rg = row0 + wave * 32 + fm * 16 + quad * 4 + r;
        pm[(size_t)rg * CS + cs] = m;
        pl[(size_t)rg * CS + cs] = l;
      }
    }
  }
}

// ---------------------------------------------------------------------------
// Kernel 2: wave-per-row lse from partials (6-step shfl_xor log-sum-exp
// butterfly over the 64 partials), then atomicAdd sum(lse)/4096.
// ---------------------------------------------------------------------------
__global__ __launch_bounds__(256) void lse_sum_kernel(
    const float* __restrict__ pm, const float* __restrict__ pl,
    float* __restrict__ out)
{
  const int row = blockIdx.x * 4 + (threadIdx.x >> 6);   // 0..4095
  const int lane = threadIdx.x & 63;
  const size_t base = (size_t)row * CS + lane;
  float m = pm[base];
  float l = pl[base];
#pragma unroll
  for (int off = 32; off > 0; off >>= 1) {
    const float m2 = __shfl_xor(m, off, 64);
    const float l2 = __shfl_xor(l, off, 64);
    const float M = fmaxf(m, m2);
    l = l * __expf(m - M) + l2 * __expf(m2 - M);
    m = M;
  }
  const float v = m + logf(l);   // identical in all 64 lanes
  __shared__ float wsum[4];
  if (lane == 0) wsum[threadIdx.x >> 6] = v;
  __syncthreads();
  if (threadIdx.x == 0)
    atomicAdd(out, (wsum[0] + wsum[1] + wsum[2] + wsum[3]) * (1.0f / 4096.0f));
}

extern "C" void kernel_launch(void* const* d_in, const int* in_sizes, int n_in,
                              void* d_out, int out_size, void* d_ws, size_t ws_size,
                              hipStream_t stream) {
  const float* o   = (const float*)d_in[0];  // (256,16,1024) f32
  const float* pos = (const float*)d_in[1];
  const float* neg = (const float*)d_in[2];
  float* out = (float*)d_out;

  float* ws = (float*)d_ws;
  float* pm = ws;                         // 4096*64 = 1 MB
  float* pl = pm + (size_t)4096 * CS;     // 4096*64 = 1 MB
  bf16_t* ob = (bf16_t*)(pl + (size_t)4096 * CS);   // 3 x 4194304 bf16
  bf16_t* pb = ob + (size_t)ARR_ELEMS;
  bf16_t* nb = pb + (size_t)ARR_ELEMS;

  cvt_kernel<<<3 * ARR_ELEMS / 8 / 256, 256, 0, stream>>>(o, pos, neg, ob, pb, nb, out);
  mega_kernel<<<NSOLVE + RT * NCS, 256, 0, stream>>>(ob, pb, nb, o, pos, pm, pl, out);
  lse_sum_kernel<<<4096 / 4, 256, 0, stream>>>(pm, pl, out);
}